// Round 7
// baseline (238.013 us; speedup 1.0000x reference)
//
#include <hip/hip_runtime.h>

#define NN 100000
#define NE 600000
#define NR 6
#define NB 6
#define NKEY (NN * NR)            // 600000 keys: dst*6 + etype
#define NCHUNK ((NKEY + 1023) / 1024)  // 586

typedef __attribute__((ext_vector_type(8))) short bfrag;       // 8 bf16 (4 VGPRs)
typedef __attribute__((ext_vector_type(8))) unsigned short uvec8;
typedef __attribute__((ext_vector_type(4))) float accvec;

__device__ __forceinline__ float bf2f(unsigned short u) {
  union { unsigned int i; float f; } v;
  v.i = ((unsigned int)u) << 16;
  return v.f;
}
__device__ __forceinline__ unsigned short f2bf(float f) {
  union { float f; unsigned int i; } v;
  v.f = f;
  return (unsigned short)((v.i + 0x7FFFu + ((v.i >> 16) & 1u)) >> 16);
}

// ---------- input conversion: nf [NN][26] f32 -> hp [NN][32] bf16 ----------
__global__ void pad_feats_bf16(const float* __restrict__ nf, unsigned short* __restrict__ hp) {
  int idx = blockIdx.x * 256 + threadIdx.x;  // one per (n, 8-col chunk)
  if (idx >= NN * 4) return;
  int n = idx >> 2, c = idx & 3;
  uvec8 o;
#pragma unroll
  for (int i = 0; i < 8; ++i) {
    int k = c * 8 + i;
    o[i] = (k < 26) ? f2bf(nf[n * 26 + k]) : (unsigned short)0;
  }
  *(uvec8*)&hp[(size_t)n * 32 + c * 8] = o;
}

// ---------- CSR build: key = dst*6 + etype ----------
__global__ void hist2(const int* __restrict__ dst, const int* __restrict__ et,
                      int* __restrict__ cnt) {
  int e = blockIdx.x * 256 + threadIdx.x;
  if (e < NE) atomicAdd(&cnt[dst[e] * NR + et[e]], 1);
}

__global__ void scanA(const int* __restrict__ cnt, int* __restrict__ partial) {
  __shared__ int ts[256];
  int t = threadIdx.x;
  int base = blockIdx.x * 1024 + t * 4;
  int s = 0;
#pragma unroll
  for (int i = 0; i < 4; ++i)
    if (base + i < NKEY) s += cnt[base + i];
  ts[t] = s;
  __syncthreads();
  for (int off = 128; off; off >>= 1) {
    if (t < off) ts[t] += ts[t + off];
    __syncthreads();
  }
  if (t == 0) partial[blockIdx.x] = ts[0];
}

__global__ void scanB(int* __restrict__ partial) {
  __shared__ int ts[256];
  int t = threadIdx.x;
  int b = t * 3;
  int v[3], s = 0;
#pragma unroll
  for (int i = 0; i < 3; ++i) {
    v[i] = (b + i < NCHUNK) ? partial[b + i] : 0;
    s += v[i];
  }
  ts[t] = s;
  __syncthreads();
  for (int off = 1; off < 256; off <<= 1) {
    int x = (t >= off) ? ts[t - off] : 0;
    __syncthreads();
    ts[t] += x;
    __syncthreads();
  }
  int run = ts[t] - s;  // exclusive
#pragma unroll
  for (int i = 0; i < 3; ++i) {
    int tmp = v[i];
    if (b + i < NCHUNK) partial[b + i] = run;
    run += tmp;
  }
}

__global__ void scanC(int* __restrict__ cnt, const int* __restrict__ partial,
                      int* __restrict__ indptr, int* __restrict__ cur) {
  __shared__ int ts[256];
  int t = threadIdx.x;
  int base = blockIdx.x * 1024 + t * 4;
  int v[4], s = 0;
#pragma unroll
  for (int i = 0; i < 4; ++i) {
    v[i] = (base + i < NKEY) ? cnt[base + i] : 0;
    s += v[i];
  }
  ts[t] = s;
  __syncthreads();
  for (int off = 1; off < 256; off <<= 1) {
    int x = (t >= off) ? ts[t - off] : 0;
    __syncthreads();
    ts[t] += x;
    __syncthreads();
  }
  int run = partial[blockIdx.x] + ts[t] - s;
#pragma unroll
  for (int i = 0; i < 4; ++i) {
    if (base + i < NKEY) {
      indptr[base + i] = run;
      cur[base + i] = run;
      run += v[i];
    }
  }
  if (blockIdx.x == 0 && t == 0) indptr[NKEY] = NE;
}

__global__ void scatter2(const int* __restrict__ et, const int* __restrict__ src,
                         const int* __restrict__ dst, int* __restrict__ cur,
                         int* __restrict__ sidx, int* __restrict__ gidx) {
  int e = blockIdx.x * 256 + threadIdx.x;
  if (e < NE) {
    int r = et[e];
    int s = src[e];
    int key = dst[e] * NR + r;
    int pos = atomicAdd(&cur[key], 1);
    sidx[pos] = s;
    gidx[pos] = r * NN + s;
  }
}

// ---------- W composition into MFMA B-fragment layout (bf16) ----------
// Layout doubles as stacked-K: kst = rel*KS + ks, table index
// (((rel*KS+ks)*NT + nt)*64 + lane)*8. rel==NR -> self weight S.
template <int IN, int OUT, int KS, int NT>
__global__ void compose_wf(const float* __restrict__ V, const float* __restrict__ C,
                           const float* __restrict__ S, unsigned short* __restrict__ Wf) {
  int idx = blockIdx.x * 256 + threadIdx.x;
  if (idx >= (NR + 1) * KS * NT * 64) return;
  int lane = idx & 63;
  int t = idx >> 6;
  int nt = t % NT; t /= NT;
  int ks = t % KS; int rel = t / KS;
  int n = nt * 16 + (lane & 15);
  int g = lane >> 4;
  uvec8 o;
#pragma unroll
  for (int i = 0; i < 8; ++i) {
    int k = ks * 32 + g * 8 + i;
    float s = 0.f;
    if (k < IN) {
      if (rel < NR) {
#pragma unroll
        for (int b = 0; b < NB; ++b) s += C[rel * NB + b] * V[((size_t)b * IN + k) * OUT + n];
      } else {
        s = S[(size_t)k * OUT + n];
      }
    }
    o[i] = f2bf(s);
  }
  *(uvec8*)&Wf[(size_t)idx * 8] = o;
}

// ---------- fused layer v3: stacked-K single GEMM per tile ----------
// Block = 256 threads (4 waves), 32 dst rows (NN % 32 == 0, no bounds checks).
// A_stacked[row][rel*K + k] = sum over edges of relation rel into row of
// h[src][k] (fp32 sum, bf16 round); rel==6 section = h[row] (self).
// One parallel build pass (all segment items independent), one barrier,
// then a dense MFMA sweep over the 7K stacked axis with the W_cat table.
template <int K, int OUT, int BPCU>
__global__ __launch_bounds__(256, BPCU) void rgcn_layer_v3(
    const unsigned short* __restrict__ h,   // [NN][K] bf16 (pre-relu'd)
    const unsigned short* __restrict__ Wf,  // stacked fragment table
    const float* __restrict__ bias,         // [OUT] f32
    const int* __restrict__ indptr,         // [NKEY+1]
    const int* __restrict__ sidx,           // [NE]
    unsigned short* __restrict__ Gout) {    // [NN][OUT] bf16
  constexpr int ROWS = 32;
  constexpr int KS = K / 32;
  constexpr int KT = 7 * KS;      // stacked k-subtiles
  constexpr int NT = OUT / 16;
  constexpr int KC = K / 8;       // 16B chunks per K
  constexpr int CT = 7 * KC;      // chunks per row (stacked)
  constexpr int KP = 7 * K + 8;   // padded LDS row stride (elems)
  constexpr int CGc = 2;          // col groups (waves split OUT)
  constexpr int NTW = NT / CGc;

  __shared__ unsigned short A[ROWS * KP];
  __shared__ int seg[ROWS * NR + 1];

  const int tid = threadIdx.x;
  const int row0 = blockIdx.x * ROWS;

  for (int i = tid; i < ROWS * NR + 1; i += 256) seg[i] = indptr[row0 * NR + i];
  __syncthreads();

  // build stacked A tile: item = (row, chunk); all items independent
  for (int idx = tid; idx < ROWS * CT; idx += 256) {
    int row = idx / CT, chunk = idx % CT;
    uvec8 o;
    if (chunk >= 6 * KC) {  // self section
      int c = chunk - 6 * KC;
      o = *(const uvec8*)&h[(size_t)(row0 + row) * K + c * 8];
    } else {
      int rel = chunk / KC, c = chunk % KC;
      int beg = seg[row * NR + rel], end = seg[row * NR + rel + 1];
      float s[8] = {0.f, 0.f, 0.f, 0.f, 0.f, 0.f, 0.f, 0.f};
      for (int e = beg; e < end; ++e) {
        uvec8 t = *(const uvec8*)&h[(size_t)sidx[e] * K + c * 8];
#pragma unroll
        for (int i = 0; i < 8; ++i) s[i] += bf2f(t[i]);
      }
#pragma unroll
      for (int i = 0; i < 8; ++i) o[i] = f2bf(s[i]);
    }
    *(uvec8*)&A[row * KP + chunk * 8] = o;
  }
  __syncthreads();

  const int lane = tid & 63;
  const int wv = tid >> 6;
  const int rh = wv >> 1;          // row half (0..1)
  const int nh = wv & 1;           // col half (0..1)
  const int abase = (rh * 16 + (lane & 15)) * KP + (lane >> 4) * 8;

  accvec acc[NTW];
#pragma unroll
  for (int j = 0; j < NTW; ++j) acc[j] = 0.f;

#pragma unroll
  for (int kst = 0; kst < KT; ++kst) {
    bfrag af = *(const bfrag*)&A[abase + kst * 32];
#pragma unroll
    for (int j = 0; j < NTW; ++j) {
      int nt = nh * NTW + j;
      bfrag bf = *(const bfrag*)&Wf[(size_t)((kst * NT + nt) * 64 + lane) * 8];
      acc[j] = __builtin_amdgcn_mfma_f32_16x16x32_bf16(af, bf, acc[j], 0, 0, 0);
    }
  }

  // epilogue: bias + relu; D layout col=lane&15, row=(lane>>4)*4+reg
  const int r0 = row0 + rh * 16 + (lane >> 4) * 4;
  const int col0 = lane & 15;
#pragma unroll
  for (int j = 0; j < NTW; ++j) {
    int c = (nh * NTW + j) * 16 + col0;
    float bv = bias[c];
#pragma unroll
    for (int r = 0; r < 4; ++r) {
      float v = fmaxf(acc[j][r] + bv, 0.f);
      Gout[(size_t)(r0 + r) * OUT + c] = f2bf(v);
    }
  }
}

// ---------- layer 3 phase A: dense per-relation transform ----------
template <int K, int OUT>
__global__ __launch_bounds__(256, 4) void rgcn_transform(
    const unsigned short* __restrict__ h,   // [NN][K] bf16 (pre-relu'd)
    const unsigned short* __restrict__ Wf,  // fragment layout, NR+1 rels
    unsigned short* __restrict__ Y) {       // [(NR+1)*NN][OUT]
  constexpr int KS = K / 32;
  constexpr int NT = OUT / 16;
  constexpr int KC = K / 8;
  constexpr int KP = K + 8;

  __shared__ unsigned short Asm[64 * KP];
  const int tid = threadIdx.x;
  const int row0 = blockIdx.x * 64;

  for (int idx = tid; idx < 64 * KC; idx += 256) {
    int j = idx / KC, c = idx - (idx / KC) * KC;
    int row = row0 + j;
    uvec8 o = 0;
    if (row < NN) o = *(const uvec8*)&h[(size_t)row * K + c * 8];
    *(uvec8*)&Asm[j * KP + c * 8] = o;
  }
  __syncthreads();

  const int lane = tid & 63;
  const int wv = tid >> 6;
  const int abase = (wv * 16 + (lane & 15)) * KP + (lane >> 4) * 8;

  bfrag af[KS];
#pragma unroll
  for (int ks = 0; ks < KS; ++ks) af[ks] = *(const bfrag*)&Asm[abase + ks * 32];

  const int r0 = row0 + wv * 16 + (lane >> 4) * 4;
  const int col0 = lane & 15;

  for (int rel = 0; rel <= NR; ++rel) {
    accvec acc[NT];
#pragma unroll
    for (int nt = 0; nt < NT; ++nt) acc[nt] = 0.f;
    const unsigned short* Wr = Wf + (size_t)rel * KS * NT * 512;
#pragma unroll
    for (int ks = 0; ks < KS; ++ks) {
#pragma unroll
      for (int nt = 0; nt < NT; ++nt) {
        bfrag bf = *(const bfrag*)&Wr[(size_t)((ks * NT + nt) * 64 + lane) * 8];
        acc[nt] = __builtin_amdgcn_mfma_f32_16x16x32_bf16(af[ks], bf, acc[nt], 0, 0, 0);
      }
    }
#pragma unroll
    for (int nt = 0; nt < NT; ++nt) {
      int c = nt * 16 + col0;
#pragma unroll
      for (int r = 0; r < 4; ++r) {
        int row = r0 + r;
        if (row < NN)
          Y[((size_t)rel * NN + row) * OUT + c] = f2bf(acc[nt][r]);
      }
    }
  }
}

// ---------- layer 3 phase B: flat segment-sum over all relations ----------
__global__ __launch_bounds__(256, 8) void rgcn_agg3(
    const unsigned short* __restrict__ Y,   // [(NR+1)*NN][32]
    const int* __restrict__ indptr,         // [NKEY+1]
    const int* __restrict__ gidx,           // [NE] = et*NN + src, sorted by dst
    const float* __restrict__ bias,         // [32]
    float* __restrict__ out) {              // [NN][32] f32
  int t = blockIdx.x * 256 + threadIdx.x;
  int row = t >> 2;
  if (row >= NN) return;
  int c = (t & 3) * 8;

  int beg = indptr[row * NR];
  int end = indptr[row * NR + NR];

  float s[8] = {0.f, 0.f, 0.f, 0.f, 0.f, 0.f, 0.f, 0.f};
  int e = beg;
  for (; e + 1 < end; e += 2) {
    int g0 = gidx[e], g1 = gidx[e + 1];
    uvec8 v0 = *(const uvec8*)&Y[(size_t)g0 * 32 + c];
    uvec8 v1 = *(const uvec8*)&Y[(size_t)g1 * 32 + c];
#pragma unroll
    for (int i = 0; i < 8; ++i) s[i] += bf2f(v0[i]) + bf2f(v1[i]);
  }
  if (e < end) {
    int g = gidx[e];
    uvec8 v = *(const uvec8*)&Y[(size_t)g * 32 + c];
#pragma unroll
    for (int i = 0; i < 8; ++i) s[i] += bf2f(v[i]);
  }
  // self
  uvec8 vs = *(const uvec8*)&Y[((size_t)NR * NN + row) * 32 + c];
#pragma unroll
  for (int i = 0; i < 8; ++i) s[i] += bf2f(vs[i]);

  float4 o0, o1;
  o0.x = fmaxf(s[0] + bias[c + 0], 0.f);
  o0.y = fmaxf(s[1] + bias[c + 1], 0.f);
  o0.z = fmaxf(s[2] + bias[c + 2], 0.f);
  o0.w = fmaxf(s[3] + bias[c + 3], 0.f);
  o1.x = fmaxf(s[4] + bias[c + 4], 0.f);
  o1.y = fmaxf(s[5] + bias[c + 5], 0.f);
  o1.z = fmaxf(s[6] + bias[c + 6], 0.f);
  o1.w = fmaxf(s[7] + bias[c + 7], 0.f);
  *(float4*)&out[(size_t)row * 32 + c] = o0;
  *(float4*)&out[(size_t)row * 32 + c + 4] = o1;
}

// ---------- host ----------
static inline char* align_up(char* p, size_t a) {
  return (char*)(((size_t)p + a - 1) & ~(a - 1));
}

extern "C" void kernel_launch(void* const* d_in, const int* in_sizes, int n_in,
                              void* d_out, int out_size, void* d_ws, size_t ws_size,
                              hipStream_t stream) {
  const float* nf = (const float*)d_in[0];
  const int* src  = (const int*)d_in[1];
  const int* dst  = (const int*)d_in[2];
  const int* et   = (const int*)d_in[3];
  const float* V1 = (const float*)d_in[4];
  const float* C1 = (const float*)d_in[5];
  const float* S1 = (const float*)d_in[6];
  const float* b1 = (const float*)d_in[7];
  const float* V2 = (const float*)d_in[8];
  const float* C2 = (const float*)d_in[9];
  const float* S2 = (const float*)d_in[10];
  const float* b2 = (const float*)d_in[11];
  const float* V3 = (const float*)d_in[12];
  const float* C3 = (const float*)d_in[13];
  const float* S3 = (const float*)d_in[14];
  const float* b3 = (const float*)d_in[15];
  float* out = (float*)d_out;

  // fragment-table element counts (u16): (NR+1)*KS*NT*64*8
  constexpr int WF1 = (NR + 1) * 1 * 4 * 512;  // 14336
  constexpr int WF2 = (NR + 1) * 2 * 8 * 512;  // 57344
  constexpr int WF3 = (NR + 1) * 4 * 2 * 512;  // 28672

  char* p = (char*)d_ws;
  int* cnt = (int*)p;                p = align_up(p + (size_t)NKEY * 4, 256);  // doubles as cur
  int* indptr = (int*)p;             p = align_up(p + (size_t)(NKEY + 1) * 4, 256);
  int* partial = (int*)p;            p = align_up(p + (size_t)NCHUNK * 4, 256);
  int* sidx = (int*)p;               p = align_up(p + (size_t)NE * 4, 256);
  int* gidx = (int*)p;               p = align_up(p + (size_t)NE * 4, 256);
  unsigned short* hp = (unsigned short*)p;  p = align_up(p + (size_t)NN * 32 * 2, 256);
  unsigned short* W1 = (unsigned short*)p;  p = align_up(p + (size_t)WF1 * 2, 256);
  unsigned short* W2 = (unsigned short*)p;  p = align_up(p + (size_t)WF2 * 2, 256);
  unsigned short* W3 = (unsigned short*)p;  p = align_up(p + (size_t)WF3 * 2, 256);
  unsigned short* G1 = (unsigned short*)p;  p = align_up(p + (size_t)NN * 64 * 2, 256);
  unsigned short* G2 = (unsigned short*)p;  p = align_up(p + (size_t)NN * 128 * 2, 256);
  unsigned short* Y3 = (unsigned short*)p;  p = align_up(p + (size_t)(NR + 1) * NN * 32 * 2, 256);

  hipMemsetAsync(cnt, 0, (size_t)NKEY * 4, stream);

  const int EB = (NE + 255) / 256;  // 2344
  pad_feats_bf16<<<(NN * 4 + 255) / 256, 256, 0, stream>>>(nf, hp);
  hist2<<<EB, 256, 0, stream>>>(dst, et, cnt);
  scanA<<<NCHUNK, 256, 0, stream>>>(cnt, partial);
  scanB<<<1, 256, 0, stream>>>(partial);
  scanC<<<NCHUNK, 256, 0, stream>>>(cnt, partial, indptr, cnt);
  scatter2<<<EB, 256, 0, stream>>>(et, src, dst, cnt, sidx, gidx);

  compose_wf<26, 64, 1, 4><<<(WF1 / 8 + 255) / 256, 256, 0, stream>>>(V1, C1, S1, W1);
  compose_wf<64, 128, 2, 8><<<(WF2 / 8 + 255) / 256, 256, 0, stream>>>(V2, C2, S2, W2);
  compose_wf<128, 32, 4, 2><<<(WF3 / 8 + 255) / 256, 256, 0, stream>>>(V3, C3, S3, W3);

  const int NB32 = NN / 32;  // 3125 (exact)
  rgcn_layer_v3<32, 64, 8><<<NB32, 256, 0, stream>>>(hp, W1, b1, indptr, sidx, G1);
  rgcn_layer_v3<64, 128, 5><<<NB32, 256, 0, stream>>>(G1, W2, b2, indptr, sidx, G2);

  // layer 3: transform-first (IN=128 > OUT=32)
  const int NBK = (NN + 63) / 64;  // 1563
  rgcn_transform<128, 32><<<NBK, 256, 0, stream>>>(G2, W3, Y3);
  rgcn_agg3<<<(NN * 4 + 255) / 256, 256, 0, stream>>>(Y3, indptr, gidx, b3, out);

  (void)in_sizes; (void)n_in; (void)out_size; (void)ws_size;
}

// Round 8
// 211.865 us; speedup vs baseline: 1.1234x; 1.1234x over previous
//
#include <hip/hip_runtime.h>

#define NN 100000
#define NE 600000
#define NR 6
#define NB 6
#define NKEY (NN * NR)            // 600000 keys: dst*6 + etype
#define NCHUNK ((NKEY + 1023) / 1024)  // 586

typedef __attribute__((ext_vector_type(8))) short bfrag;       // 8 bf16 (4 VGPRs)
typedef __attribute__((ext_vector_type(8))) unsigned short uvec8;
typedef __attribute__((ext_vector_type(4))) float accvec;

__device__ __forceinline__ float bf2f(unsigned short u) {
  union { unsigned int i; float f; } v;
  v.i = ((unsigned int)u) << 16;
  return v.f;
}
__device__ __forceinline__ unsigned short f2bf(float f) {
  union { float f; unsigned int i; } v;
  v.f = f;
  return (unsigned short)((v.i + 0x7FFFu + ((v.i >> 16) & 1u)) >> 16);
}

// ---------- input conversion: nf [NN][26] f32 -> hp [NN][32] bf16 ----------
__global__ void pad_feats_bf16(const float* __restrict__ nf, unsigned short* __restrict__ hp) {
  int idx = blockIdx.x * 256 + threadIdx.x;  // one per (n, 8-col chunk)
  if (idx >= NN * 4) return;
  int n = idx >> 2, c = idx & 3;
  uvec8 o;
#pragma unroll
  for (int i = 0; i < 8; ++i) {
    int k = c * 8 + i;
    o[i] = (k < 26) ? f2bf(nf[n * 26 + k]) : (unsigned short)0;
  }
  *(uvec8*)&hp[(size_t)n * 32 + c * 8] = o;
}

// ---------- CSR build: key = dst*6 + etype ----------
__global__ void hist2(const int* __restrict__ dst, const int* __restrict__ et,
                      int* __restrict__ cnt) {
  int e = blockIdx.x * 256 + threadIdx.x;
  if (e < NE) atomicAdd(&cnt[dst[e] * NR + et[e]], 1);
}

__global__ void scanA(const int* __restrict__ cnt, int* __restrict__ partial) {
  __shared__ int ts[256];
  int t = threadIdx.x;
  int base = blockIdx.x * 1024 + t * 4;
  int s = 0;
#pragma unroll
  for (int i = 0; i < 4; ++i)
    if (base + i < NKEY) s += cnt[base + i];
  ts[t] = s;
  __syncthreads();
  for (int off = 128; off; off >>= 1) {
    if (t < off) ts[t] += ts[t + off];
    __syncthreads();
  }
  if (t == 0) partial[blockIdx.x] = ts[0];
}

__global__ void scanB(int* __restrict__ partial) {
  __shared__ int ts[256];
  int t = threadIdx.x;
  int b = t * 3;
  int v[3], s = 0;
#pragma unroll
  for (int i = 0; i < 3; ++i) {
    v[i] = (b + i < NCHUNK) ? partial[b + i] : 0;
    s += v[i];
  }
  ts[t] = s;
  __syncthreads();
  for (int off = 1; off < 256; off <<= 1) {
    int x = (t >= off) ? ts[t - off] : 0;
    __syncthreads();
    ts[t] += x;
    __syncthreads();
  }
  int run = ts[t] - s;  // exclusive
#pragma unroll
  for (int i = 0; i < 3; ++i) {
    int tmp = v[i];
    if (b + i < NCHUNK) partial[b + i] = run;
    run += tmp;
  }
}

__global__ void scanC(int* __restrict__ cnt, const int* __restrict__ partial,
                      int* __restrict__ indptr, int* __restrict__ cur) {
  __shared__ int ts[256];
  int t = threadIdx.x;
  int base = blockIdx.x * 1024 + t * 4;
  int v[4], s = 0;
#pragma unroll
  for (int i = 0; i < 4; ++i) {
    v[i] = (base + i < NKEY) ? cnt[base + i] : 0;
    s += v[i];
  }
  ts[t] = s;
  __syncthreads();
  for (int off = 1; off < 256; off <<= 1) {
    int x = (t >= off) ? ts[t - off] : 0;
    __syncthreads();
    ts[t] += x;
    __syncthreads();
  }
  int run = partial[blockIdx.x] + ts[t] - s;
#pragma unroll
  for (int i = 0; i < 4; ++i) {
    if (base + i < NKEY) {
      indptr[base + i] = run;
      cur[base + i] = run;
      run += v[i];
    }
  }
  if (blockIdx.x == 0 && t == 0) indptr[NKEY] = NE;
}

__global__ void scatter2(const int* __restrict__ et, const int* __restrict__ src,
                         const int* __restrict__ dst, int* __restrict__ cur,
                         int* __restrict__ sidx, int* __restrict__ gidx) {
  int e = blockIdx.x * 256 + threadIdx.x;
  if (e < NE) {
    int r = et[e];
    int s = src[e];
    int key = dst[e] * NR + r;
    int pos = atomicAdd(&cur[key], 1);
    sidx[pos] = s;
    gidx[pos] = r * NN + s;
  }
}

// ---------- W composition into MFMA B-fragment layout (bf16) ----------
// Layout doubles as stacked-K: kst = rel*KS + ks, table index
// (((rel*KS+ks)*NT + nt)*64 + lane)*8. rel==NR -> self weight S.
template <int IN, int OUT, int KS, int NT>
__global__ void compose_wf(const float* __restrict__ V, const float* __restrict__ C,
                           const float* __restrict__ S, unsigned short* __restrict__ Wf) {
  int idx = blockIdx.x * 256 + threadIdx.x;
  if (idx >= (NR + 1) * KS * NT * 64) return;
  int lane = idx & 63;
  int t = idx >> 6;
  int nt = t % NT; t /= NT;
  int ks = t % KS; int rel = t / KS;
  int n = nt * 16 + (lane & 15);
  int g = lane >> 4;
  uvec8 o;
#pragma unroll
  for (int i = 0; i < 8; ++i) {
    int k = ks * 32 + g * 8 + i;
    float s = 0.f;
    if (k < IN) {
      if (rel < NR) {
#pragma unroll
        for (int b = 0; b < NB; ++b) s += C[rel * NB + b] * V[((size_t)b * IN + k) * OUT + n];
      } else {
        s = S[(size_t)k * OUT + n];
      }
    }
    o[i] = f2bf(s);
  }
  *(uvec8*)&Wf[(size_t)idx * 8] = o;
}

// ---------- fused layer v4: staged edges + register segment-sums + stacked GEMM ----------
// Block = 256 threads (4 waves), 32 dst rows. Batch loop: stage up to MAXE edges'
// source rows into LDS with a STATICALLY UNROLLED flat load loop (all loads
// independent -> max MLP), then per-thread fp32 register accumulators sum each
// (row,rel,chunk) item's segment slice from LDS. Accumulators persist across
// batches (exact). After the loop, pack bf16 stacked A tile (aliases msg
// buffer) and run one dense MFMA sweep over the 7K stacked axis.
template <int K, int OUT, int MAXE, int BPCU>
__global__ __launch_bounds__(256, BPCU) void rgcn_layer_v4(
    const unsigned short* __restrict__ h,   // [NN][K] bf16 (pre-relu'd)
    const unsigned short* __restrict__ Wf,  // stacked fragment table
    const float* __restrict__ bias,         // [OUT] f32
    const int* __restrict__ indptr,         // [NKEY+1]
    const int* __restrict__ sidx,           // [NE]
    unsigned short* __restrict__ Gout) {    // [NN][OUT] bf16
  constexpr int ROWS = 32;
  constexpr int KS = K / 32;
  constexpr int KT = 7 * KS;           // stacked k-subtiles
  constexpr int NT = OUT / 16;
  constexpr int NTW = NT / 2;          // waves split OUT in 2 halves
  constexpr int KC = K / 8;            // 16B chunks per K
  constexpr int CT = 7 * KC;           // chunks per row (stacked)
  constexpr int ITEMS = (ROWS * CT + 255) / 256;
  constexpr int KP = 7 * K + 8;        // A-tile row stride (elems)
  constexpr int MSTRIDE = K + 8;       // msg row stride (elems)
  constexpr int LDSE = (ROWS * KP > MAXE * MSTRIDE) ? ROWS * KP : MAXE * MSTRIDE;
  constexpr int SITER = MAXE * KC / 256;  // static staging iterations

  __shared__ unsigned short A[LDSE];   // msg buffer first, A tile after
  __shared__ int seg[ROWS * NR + 1];

  const int tid = threadIdx.x;
  const int row0 = blockIdx.x * ROWS;

  for (int i = tid; i < ROWS * NR + 1; i += 256) seg[i] = indptr[row0 * NR + i];
  __syncthreads();

  const int E0 = seg[0];
  const int E1 = seg[ROWS * NR];

  float sum[ITEMS][8];
#pragma unroll
  for (int i = 0; i < ITEMS; ++i)
#pragma unroll
    for (int q = 0; q < 8; ++q) sum[i][q] = 0.f;

  for (int b0 = E0; b0 < E1; b0 += MAXE) {
    const int bcount = min(MAXE, E1 - b0);
    __syncthreads();  // msg free (prev accumulate done)

    // stage: static unrolled flat gather (independent loads; clamp tail)
#pragma unroll
    for (int i = 0; i < SITER; ++i) {
      int idx = tid + i * 256;
      int e = idx / KC;
      int c = idx & (KC - 1);
      int ec = min(e, bcount - 1);
      int s = sidx[b0 + ec];
      *(uvec8*)&A[e * MSTRIDE + c * 8] = *(const uvec8*)&h[(size_t)s * K + c * 8];
    }
    __syncthreads();

    // accumulate from LDS into per-thread fp32 regs
#pragma unroll
    for (int i = 0; i < ITEMS; ++i) {
      int idx = tid + i * 256;
      if (idx < ROWS * CT) {
        int row = idx / CT, chunk = idx % CT;
        if (chunk < 6 * KC) {
          int rel = chunk / KC, c = chunk & (KC - 1);
          int beg = seg[row * NR + rel], end = seg[row * NR + rel + 1];
          int lo = max(beg, b0), hi = min(end, b0 + bcount);
          for (int e = lo; e < hi; ++e) {
            uvec8 t = *(const uvec8*)&A[(e - b0) * MSTRIDE + c * 8];
#pragma unroll
            for (int q = 0; q < 8; ++q) sum[i][q] += bf2f(t[q]);
          }
        }
      }
    }
  }

  __syncthreads();  // accumulation done; msg buffer now reusable as A tile

  // pack stacked bf16 A tile
#pragma unroll
  for (int i = 0; i < ITEMS; ++i) {
    int idx = tid + i * 256;
    if (idx < ROWS * CT) {
      int row = idx / CT, chunk = idx % CT;
      uvec8 o;
      if (chunk >= 6 * KC) {  // self section: direct copy
        int c = chunk - 6 * KC;
        o = *(const uvec8*)&h[(size_t)(row0 + row) * K + c * 8];
      } else {
#pragma unroll
        for (int q = 0; q < 8; ++q) o[q] = f2bf(sum[i][q]);
      }
      *(uvec8*)&A[row * KP + chunk * 8] = o;
    }
  }
  __syncthreads();

  // dense MFMA sweep over stacked K
  const int lane = tid & 63;
  const int wv = tid >> 6;
  const int rh = wv >> 1;          // row half (0..1)
  const int nh = wv & 1;           // col half (0..1)
  const int abase = (rh * 16 + (lane & 15)) * KP + (lane >> 4) * 8;

  accvec acc[NTW];
#pragma unroll
  for (int j = 0; j < NTW; ++j) acc[j] = 0.f;

#pragma unroll
  for (int kst = 0; kst < KT; ++kst) {
    bfrag af = *(const bfrag*)&A[abase + kst * 32];
#pragma unroll
    for (int j = 0; j < NTW; ++j) {
      int nt = nh * NTW + j;
      bfrag bf = *(const bfrag*)&Wf[(size_t)((kst * NT + nt) * 64 + lane) * 8];
      acc[j] = __builtin_amdgcn_mfma_f32_16x16x32_bf16(af, bf, acc[j], 0, 0, 0);
    }
  }

  // epilogue: bias + relu; D layout col=lane&15, row=(lane>>4)*4+reg
  const int r0 = row0 + rh * 16 + (lane >> 4) * 4;
  const int col0 = lane & 15;
#pragma unroll
  for (int j = 0; j < NTW; ++j) {
    int c = (nh * NTW + j) * 16 + col0;
    float bv = bias[c];
#pragma unroll
    for (int r = 0; r < 4; ++r) {
      float v = fmaxf(acc[j][r] + bv, 0.f);
      Gout[(size_t)(r0 + r) * OUT + c] = f2bf(v);
    }
  }
}

// ---------- layer 3 phase A: dense per-relation transform ----------
template <int K, int OUT>
__global__ __launch_bounds__(256, 4) void rgcn_transform(
    const unsigned short* __restrict__ h,   // [NN][K] bf16 (pre-relu'd)
    const unsigned short* __restrict__ Wf,  // fragment layout, NR+1 rels
    unsigned short* __restrict__ Y) {       // [(NR+1)*NN][OUT]
  constexpr int KS = K / 32;
  constexpr int NT = OUT / 16;
  constexpr int KC = K / 8;
  constexpr int KP = K + 8;

  __shared__ unsigned short Asm[64 * KP];
  const int tid = threadIdx.x;
  const int row0 = blockIdx.x * 64;

  for (int idx = tid; idx < 64 * KC; idx += 256) {
    int j = idx / KC, c = idx - (idx / KC) * KC;
    int row = row0 + j;
    uvec8 o = 0;
    if (row < NN) o = *(const uvec8*)&h[(size_t)row * K + c * 8];
    *(uvec8*)&Asm[j * KP + c * 8] = o;
  }
  __syncthreads();

  const int lane = tid & 63;
  const int wv = tid >> 6;
  const int abase = (wv * 16 + (lane & 15)) * KP + (lane >> 4) * 8;

  bfrag af[KS];
#pragma unroll
  for (int ks = 0; ks < KS; ++ks) af[ks] = *(const bfrag*)&Asm[abase + ks * 32];

  const int r0 = row0 + wv * 16 + (lane >> 4) * 4;
  const int col0 = lane & 15;

  for (int rel = 0; rel <= NR; ++rel) {
    accvec acc[NT];
#pragma unroll
    for (int nt = 0; nt < NT; ++nt) acc[nt] = 0.f;
    const unsigned short* Wr = Wf + (size_t)rel * KS * NT * 512;
#pragma unroll
    for (int ks = 0; ks < KS; ++ks) {
#pragma unroll
      for (int nt = 0; nt < NT; ++nt) {
        bfrag bf = *(const bfrag*)&Wr[(size_t)((ks * NT + nt) * 64 + lane) * 8];
        acc[nt] = __builtin_amdgcn_mfma_f32_16x16x32_bf16(af[ks], bf, acc[nt], 0, 0, 0);
      }
    }
#pragma unroll
    for (int nt = 0; nt < NT; ++nt) {
      int c = nt * 16 + col0;
#pragma unroll
      for (int r = 0; r < 4; ++r) {
        int row = r0 + r;
        if (row < NN)
          Y[((size_t)rel * NN + row) * OUT + c] = f2bf(acc[nt][r]);
      }
    }
  }
}

// ---------- layer 3 phase B: flat segment-sum over all relations ----------
__global__ __launch_bounds__(256, 8) void rgcn_agg3(
    const unsigned short* __restrict__ Y,   // [(NR+1)*NN][32]
    const int* __restrict__ indptr,         // [NKEY+1]
    const int* __restrict__ gidx,           // [NE] = et*NN + src, sorted by dst
    const float* __restrict__ bias,         // [32]
    float* __restrict__ out) {              // [NN][32] f32
  int t = blockIdx.x * 256 + threadIdx.x;
  int row = t >> 2;
  if (row >= NN) return;
  int c = (t & 3) * 8;

  int beg = indptr[row * NR];
  int end = indptr[row * NR + NR];

  float s[8] = {0.f, 0.f, 0.f, 0.f, 0.f, 0.f, 0.f, 0.f};
  int e = beg;
  for (; e + 3 < end; e += 4) {
    int g0 = gidx[e], g1 = gidx[e + 1], g2 = gidx[e + 2], g3 = gidx[e + 3];
    uvec8 v0 = *(const uvec8*)&Y[(size_t)g0 * 32 + c];
    uvec8 v1 = *(const uvec8*)&Y[(size_t)g1 * 32 + c];
    uvec8 v2 = *(const uvec8*)&Y[(size_t)g2 * 32 + c];
    uvec8 v3 = *(const uvec8*)&Y[(size_t)g3 * 32 + c];
#pragma unroll
    for (int i = 0; i < 8; ++i)
      s[i] += (bf2f(v0[i]) + bf2f(v1[i])) + (bf2f(v2[i]) + bf2f(v3[i]));
  }
  for (; e < end; ++e) {
    int g = gidx[e];
    uvec8 v = *(const uvec8*)&Y[(size_t)g * 32 + c];
#pragma unroll
    for (int i = 0; i < 8; ++i) s[i] += bf2f(v[i]);
  }
  // self
  uvec8 vs = *(const uvec8*)&Y[((size_t)NR * NN + row) * 32 + c];
#pragma unroll
  for (int i = 0; i < 8; ++i) s[i] += bf2f(vs[i]);

  float4 o0, o1;
  o0.x = fmaxf(s[0] + bias[c + 0], 0.f);
  o0.y = fmaxf(s[1] + bias[c + 1], 0.f);
  o0.z = fmaxf(s[2] + bias[c + 2], 0.f);
  o0.w = fmaxf(s[3] + bias[c + 3], 0.f);
  o1.x = fmaxf(s[4] + bias[c + 4], 0.f);
  o1.y = fmaxf(s[5] + bias[c + 5], 0.f);
  o1.z = fmaxf(s[6] + bias[c + 6], 0.f);
  o1.w = fmaxf(s[7] + bias[c + 7], 0.f);
  *(float4*)&out[(size_t)row * 32 + c] = o0;
  *(float4*)&out[(size_t)row * 32 + c + 4] = o1;
}

// ---------- host ----------
static inline char* align_up(char* p, size_t a) {
  return (char*)(((size_t)p + a - 1) & ~(a - 1));
}

extern "C" void kernel_launch(void* const* d_in, const int* in_sizes, int n_in,
                              void* d_out, int out_size, void* d_ws, size_t ws_size,
                              hipStream_t stream) {
  const float* nf = (const float*)d_in[0];
  const int* src  = (const int*)d_in[1];
  const int* dst  = (const int*)d_in[2];
  const int* et   = (const int*)d_in[3];
  const float* V1 = (const float*)d_in[4];
  const float* C1 = (const float*)d_in[5];
  const float* S1 = (const float*)d_in[6];
  const float* b1 = (const float*)d_in[7];
  const float* V2 = (const float*)d_in[8];
  const float* C2 = (const float*)d_in[9];
  const float* S2 = (const float*)d_in[10];
  const float* b2 = (const float*)d_in[11];
  const float* V3 = (const float*)d_in[12];
  const float* C3 = (const float*)d_in[13];
  const float* S3 = (const float*)d_in[14];
  const float* b3 = (const float*)d_in[15];
  float* out = (float*)d_out;

  // fragment-table element counts (u16): (NR+1)*KS*NT*64*8
  constexpr int WF1 = (NR + 1) * 1 * 4 * 512;  // 14336
  constexpr int WF2 = (NR + 1) * 2 * 8 * 512;  // 57344
  constexpr int WF3 = (NR + 1) * 4 * 2 * 512;  // 28672

  char* p = (char*)d_ws;
  int* cnt = (int*)p;                p = align_up(p + (size_t)NKEY * 4, 256);  // doubles as cur
  int* indptr = (int*)p;             p = align_up(p + (size_t)(NKEY + 1) * 4, 256);
  int* partial = (int*)p;            p = align_up(p + (size_t)NCHUNK * 4, 256);
  int* sidx = (int*)p;               p = align_up(p + (size_t)NE * 4, 256);
  int* gidx = (int*)p;               p = align_up(p + (size_t)NE * 4, 256);
  unsigned short* hp = (unsigned short*)p;  p = align_up(p + (size_t)NN * 32 * 2, 256);
  unsigned short* W1 = (unsigned short*)p;  p = align_up(p + (size_t)WF1 * 2, 256);
  unsigned short* W2 = (unsigned short*)p;  p = align_up(p + (size_t)WF2 * 2, 256);
  unsigned short* W3 = (unsigned short*)p;  p = align_up(p + (size_t)WF3 * 2, 256);
  unsigned short* G1 = (unsigned short*)p;  p = align_up(p + (size_t)NN * 64 * 2, 256);
  unsigned short* G2 = (unsigned short*)p;  p = align_up(p + (size_t)NN * 128 * 2, 256);
  unsigned short* Y3 = (unsigned short*)p;  p = align_up(p + (size_t)(NR + 1) * NN * 32 * 2, 256);

  hipMemsetAsync(cnt, 0, (size_t)NKEY * 4, stream);

  const int EB = (NE + 255) / 256;  // 2344
  pad_feats_bf16<<<(NN * 4 + 255) / 256, 256, 0, stream>>>(nf, hp);
  hist2<<<EB, 256, 0, stream>>>(dst, et, cnt);
  scanA<<<NCHUNK, 256, 0, stream>>>(cnt, partial);
  scanB<<<1, 256, 0, stream>>>(partial);
  scanC<<<NCHUNK, 256, 0, stream>>>(cnt, partial, indptr, cnt);
  scatter2<<<EB, 256, 0, stream>>>(et, src, dst, cnt, sidx, gidx);

  compose_wf<26, 64, 1, 4><<<(WF1 / 8 + 255) / 256, 256, 0, stream>>>(V1, C1, S1, W1);
  compose_wf<64, 128, 2, 8><<<(WF2 / 8 + 255) / 256, 256, 0, stream>>>(V2, C2, S2, W2);
  compose_wf<128, 32, 4, 2><<<(WF3 / 8 + 255) / 256, 256, 0, stream>>>(V3, C3, S3, W3);

  const int NB32 = NN / 32;  // 3125 (exact)
  rgcn_layer_v4<32, 64, 192, 4><<<NB32, 256, 0, stream>>>(hp, W1, b1, indptr, sidx, G1);
  rgcn_layer_v4<64, 128, 192, 4><<<NB32, 256, 0, stream>>>(G1, W2, b2, indptr, sidx, G2);

  // layer 3: transform-first (IN=128 > OUT=32)
  const int NBK = (NN + 63) / 64;  // 1563
  rgcn_transform<128, 32><<<NBK, 256, 0, stream>>>(G2, W3, Y3);
  rgcn_agg3<<<(NN * 4 + 255) / 256, 256, 0, stream>>>(Y3, indptr, gidx, b3, out);

  (void)in_sizes; (void)n_in; (void)out_size; (void)ws_size;
}

// Round 9
// 204.979 us; speedup vs baseline: 1.1612x; 1.0336x over previous
//
#include <hip/hip_runtime.h>

#define NN 100000
#define NE 600000
#define NR 6
#define NB 6
#define NKEY (NN * NR)            // 600000 keys: dst*6 + etype
#define NCHUNK ((NKEY + 1023) / 1024)  // 586

typedef __attribute__((ext_vector_type(8))) short bfrag;       // 8 bf16 (4 VGPRs)
typedef __attribute__((ext_vector_type(8))) unsigned short uvec8;
typedef __attribute__((ext_vector_type(4))) float accvec;

__device__ __forceinline__ float bf2f(unsigned short u) {
  union { unsigned int i; float f; } v;
  v.i = ((unsigned int)u) << 16;
  return v.f;
}
__device__ __forceinline__ unsigned short f2bf(float f) {
  union { float f; unsigned int i; } v;
  v.f = f;
  return (unsigned short)((v.i + 0x7FFFu + ((v.i >> 16) & 1u)) >> 16);
}

// ---------- input conversion: nf [NN][26] f32 -> hp [NN][32] bf16 ----------
__global__ void pad_feats_bf16(const float* __restrict__ nf, unsigned short* __restrict__ hp) {
  int idx = blockIdx.x * 256 + threadIdx.x;  // one per (n, 8-col chunk)
  if (idx >= NN * 4) return;
  int n = idx >> 2, c = idx & 3;
  uvec8 o;
#pragma unroll
  for (int i = 0; i < 8; ++i) {
    int k = c * 8 + i;
    o[i] = (k < 26) ? f2bf(nf[n * 26 + k]) : (unsigned short)0;
  }
  *(uvec8*)&hp[(size_t)n * 32 + c * 8] = o;
}

// ---------- CSR build: key = dst*6 + etype ----------
__global__ void hist2(const int* __restrict__ dst, const int* __restrict__ et,
                      int* __restrict__ cnt) {
  int e = blockIdx.x * 256 + threadIdx.x;
  if (e < NE) atomicAdd(&cnt[dst[e] * NR + et[e]], 1);
}

__global__ void scanA(const int* __restrict__ cnt, int* __restrict__ partial) {
  __shared__ int ts[256];
  int t = threadIdx.x;
  int base = blockIdx.x * 1024 + t * 4;
  int s = 0;
#pragma unroll
  for (int i = 0; i < 4; ++i)
    if (base + i < NKEY) s += cnt[base + i];
  ts[t] = s;
  __syncthreads();
  for (int off = 128; off; off >>= 1) {
    if (t < off) ts[t] += ts[t + off];
    __syncthreads();
  }
  if (t == 0) partial[blockIdx.x] = ts[0];
}

__global__ void scanB(int* __restrict__ partial) {
  __shared__ int ts[256];
  int t = threadIdx.x;
  int b = t * 3;
  int v[3], s = 0;
#pragma unroll
  for (int i = 0; i < 3; ++i) {
    v[i] = (b + i < NCHUNK) ? partial[b + i] : 0;
    s += v[i];
  }
  ts[t] = s;
  __syncthreads();
  for (int off = 1; off < 256; off <<= 1) {
    int x = (t >= off) ? ts[t - off] : 0;
    __syncthreads();
    ts[t] += x;
    __syncthreads();
  }
  int run = ts[t] - s;  // exclusive
#pragma unroll
  for (int i = 0; i < 3; ++i) {
    int tmp = v[i];
    if (b + i < NCHUNK) partial[b + i] = run;
    run += tmp;
  }
}

__global__ void scanC(int* __restrict__ cnt, const int* __restrict__ partial,
                      int* __restrict__ indptr, int* __restrict__ cur) {
  __shared__ int ts[256];
  int t = threadIdx.x;
  int base = blockIdx.x * 1024 + t * 4;
  int v[4], s = 0;
#pragma unroll
  for (int i = 0; i < 4; ++i) {
    v[i] = (base + i < NKEY) ? cnt[base + i] : 0;
    s += v[i];
  }
  ts[t] = s;
  __syncthreads();
  for (int off = 1; off < 256; off <<= 1) {
    int x = (t >= off) ? ts[t - off] : 0;
    __syncthreads();
    ts[t] += x;
    __syncthreads();
  }
  int run = partial[blockIdx.x] + ts[t] - s;
#pragma unroll
  for (int i = 0; i < 4; ++i) {
    if (base + i < NKEY) {
      indptr[base + i] = run;
      cur[base + i] = run;
      run += v[i];
    }
  }
  if (blockIdx.x == 0 && t == 0) indptr[NKEY] = NE;
}

__global__ void scatter2(const int* __restrict__ et, const int* __restrict__ src,
                         const int* __restrict__ dst, int* __restrict__ cur,
                         int* __restrict__ sidx, int* __restrict__ gidx) {
  int e = blockIdx.x * 256 + threadIdx.x;
  if (e < NE) {
    int r = et[e];
    int s = src[e];
    int key = dst[e] * NR + r;
    int pos = atomicAdd(&cur[key], 1);
    sidx[pos] = s;
    gidx[pos] = r * NN + s;
  }
}

// ---------- W composition into MFMA B-fragment layout (bf16) ----------
// Layout doubles as stacked-K: kst = rel*KS + ks, table index
// (((rel*KS+ks)*NT + nt)*64 + lane)*8. rel==NR -> self weight S.
template <int IN, int OUT, int KS, int NT>
__global__ void compose_wf(const float* __restrict__ V, const float* __restrict__ C,
                           const float* __restrict__ S, unsigned short* __restrict__ Wf) {
  int idx = blockIdx.x * 256 + threadIdx.x;
  if (idx >= (NR + 1) * KS * NT * 64) return;
  int lane = idx & 63;
  int t = idx >> 6;
  int nt = t % NT; t /= NT;
  int ks = t % KS; int rel = t / KS;
  int n = nt * 16 + (lane & 15);
  int g = lane >> 4;
  uvec8 o;
#pragma unroll
  for (int i = 0; i < 8; ++i) {
    int k = ks * 32 + g * 8 + i;
    float s = 0.f;
    if (k < IN) {
      if (rel < NR) {
#pragma unroll
        for (int b = 0; b < NB; ++b) s += C[rel * NB + b] * V[((size_t)b * IN + k) * OUT + n];
      } else {
        s = S[(size_t)k * OUT + n];
      }
    }
    o[i] = f2bf(s);
  }
  *(uvec8*)&Wf[(size_t)idx * 8] = o;
}

// ---------- fused layer v5: small tile (16 rows) for 8 blocks/CU occupancy ----------
// Batch loop: stage up to MAXE edges' source rows into LDS (statically unrolled
// independent loads -> max MLP), then per-thread fp32 register accumulators sum
// each (row,rel,chunk) item's segment slice from LDS. Accumulators persist
// across batches. Then pack stacked bf16 A tile (aliases msg buffer) and one
// dense MFMA sweep over the 7K stacked axis; 4 waves split OUT 4-ways.
template <int K, int OUT, int MAXE, int BPEU>
__global__ __launch_bounds__(256, BPEU) void rgcn_layer_v5(
    const unsigned short* __restrict__ h,   // [NN][K] bf16 (pre-relu'd)
    const unsigned short* __restrict__ Wf,  // stacked fragment table
    const float* __restrict__ bias,         // [OUT] f32
    const int* __restrict__ indptr,         // [NKEY+1]
    const int* __restrict__ sidx,           // [NE]
    unsigned short* __restrict__ Gout) {    // [NN][OUT] bf16
  constexpr int ROWS = 16;
  constexpr int KS = K / 32;
  constexpr int KT = 7 * KS;           // stacked k-subtiles
  constexpr int NT = OUT / 16;
  constexpr int NTW = NT / 4;          // waves split OUT in 4
  constexpr int KC = K / 8;            // 16B chunks per K
  constexpr int CT = 7 * KC;           // chunks per row (stacked)
  constexpr int ITEMS = (ROWS * CT + 255) / 256;
  constexpr int KP = 7 * K + 8;        // A-tile row stride (elems)
  constexpr int MSTRIDE = K + 8;       // msg row stride (elems)
  constexpr int LDSE = (ROWS * KP > MAXE * MSTRIDE) ? ROWS * KP : MAXE * MSTRIDE;
  constexpr int SITER = MAXE * KC / 256;  // static staging iterations

  __shared__ unsigned short A[LDSE];   // msg buffer first, A tile after
  __shared__ int seg[ROWS * NR + 1];

  const int tid = threadIdx.x;
  const int row0 = blockIdx.x * ROWS;

  if (tid < ROWS * NR + 1) seg[tid] = indptr[row0 * NR + tid];
  __syncthreads();

  const int E0 = seg[0];
  const int E1 = seg[ROWS * NR];

  float sum[ITEMS][8];
#pragma unroll
  for (int i = 0; i < ITEMS; ++i)
#pragma unroll
    for (int q = 0; q < 8; ++q) sum[i][q] = 0.f;

  for (int b0 = E0; b0 < E1; b0 += MAXE) {
    const int bcount = min(MAXE, E1 - b0);
    __syncthreads();  // msg free (prev accumulate done)

    // stage: static unrolled flat gather (independent loads; clamp tail)
#pragma unroll
    for (int i = 0; i < SITER; ++i) {
      int idx = tid + i * 256;
      int e = idx / KC;
      int c = idx & (KC - 1);
      int ec = min(e, bcount - 1);
      int s = sidx[b0 + ec];
      *(uvec8*)&A[e * MSTRIDE + c * 8] = *(const uvec8*)&h[(size_t)s * K + c * 8];
    }
    __syncthreads();

    // accumulate from LDS into per-thread fp32 regs
#pragma unroll
    for (int i = 0; i < ITEMS; ++i) {
      int idx = tid + i * 256;
      if (idx < ROWS * CT) {
        int row = idx / CT, chunk = idx % CT;
        if (chunk < 6 * KC) {
          int rel = chunk / KC, c = chunk & (KC - 1);
          int beg = seg[row * NR + rel], end = seg[row * NR + rel + 1];
          int lo = max(beg, b0), hi = min(end, b0 + bcount);
          for (int e = lo; e < hi; ++e) {
            uvec8 t = *(const uvec8*)&A[(e - b0) * MSTRIDE + c * 8];
#pragma unroll
            for (int q = 0; q < 8; ++q) sum[i][q] += bf2f(t[q]);
          }
        }
      }
    }
  }

  __syncthreads();  // accumulation done; msg buffer now reusable as A tile

  // pack stacked bf16 A tile
#pragma unroll
  for (int i = 0; i < ITEMS; ++i) {
    int idx = tid + i * 256;
    if (idx < ROWS * CT) {
      int row = idx / CT, chunk = idx % CT;
      uvec8 o;
      if (chunk >= 6 * KC) {  // self section: direct copy
        int c = chunk - 6 * KC;
        o = *(const uvec8*)&h[(size_t)(row0 + row) * K + c * 8];
      } else {
#pragma unroll
        for (int q = 0; q < 8; ++q) o[q] = f2bf(sum[i][q]);
      }
      *(uvec8*)&A[row * KP + chunk * 8] = o;
    }
  }
  __syncthreads();

  // dense MFMA sweep over stacked K; waves split OUT 4-ways
  const int lane = tid & 63;
  const int wv = tid >> 6;
  const int abase = (lane & 15) * KP + (lane >> 4) * 8;

  accvec acc[NTW];
#pragma unroll
  for (int j = 0; j < NTW; ++j) acc[j] = 0.f;

#pragma unroll
  for (int kst = 0; kst < KT; ++kst) {
    bfrag af = *(const bfrag*)&A[abase + kst * 32];
#pragma unroll
    for (int j = 0; j < NTW; ++j) {
      int nt = wv * NTW + j;
      bfrag bf = *(const bfrag*)&Wf[(size_t)((kst * NT + nt) * 64 + lane) * 8];
      acc[j] = __builtin_amdgcn_mfma_f32_16x16x32_bf16(af, bf, acc[j], 0, 0, 0);
    }
  }

  // epilogue: bias + relu; D layout col=lane&15, row=(lane>>4)*4+reg
  const int r0 = row0 + (lane >> 4) * 4;
  const int col0 = lane & 15;
#pragma unroll
  for (int j = 0; j < NTW; ++j) {
    int c = (wv * NTW + j) * 16 + col0;
    float bv = bias[c];
#pragma unroll
    for (int r = 0; r < 4; ++r) {
      float v = fmaxf(acc[j][r] + bv, 0.f);
      Gout[(size_t)(r0 + r) * OUT + c] = f2bf(v);
    }
  }
}

// ---------- layer 3 phase A: dense per-relation transform ----------
template <int K, int OUT>
__global__ __launch_bounds__(256, 4) void rgcn_transform(
    const unsigned short* __restrict__ h,   // [NN][K] bf16 (pre-relu'd)
    const unsigned short* __restrict__ Wf,  // fragment layout, NR+1 rels
    unsigned short* __restrict__ Y) {       // [(NR+1)*NN][OUT]
  constexpr int KS = K / 32;
  constexpr int NT = OUT / 16;
  constexpr int KC = K / 8;
  constexpr int KP = K + 8;

  __shared__ unsigned short Asm[64 * KP];
  const int tid = threadIdx.x;
  const int row0 = blockIdx.x * 64;

  for (int idx = tid; idx < 64 * KC; idx += 256) {
    int j = idx / KC, c = idx - (idx / KC) * KC;
    int row = row0 + j;
    uvec8 o = 0;
    if (row < NN) o = *(const uvec8*)&h[(size_t)row * K + c * 8];
    *(uvec8*)&Asm[j * KP + c * 8] = o;
  }
  __syncthreads();

  const int lane = tid & 63;
  const int wv = tid >> 6;
  const int abase = (wv * 16 + (lane & 15)) * KP + (lane >> 4) * 8;

  bfrag af[KS];
#pragma unroll
  for (int ks = 0; ks < KS; ++ks) af[ks] = *(const bfrag*)&Asm[abase + ks * 32];

  const int r0 = row0 + wv * 16 + (lane >> 4) * 4;
  const int col0 = lane & 15;

  for (int rel = 0; rel <= NR; ++rel) {
    accvec acc[NT];
#pragma unroll
    for (int nt = 0; nt < NT; ++nt) acc[nt] = 0.f;
    const unsigned short* Wr = Wf + (size_t)rel * KS * NT * 512;
#pragma unroll
    for (int ks = 0; ks < KS; ++ks) {
#pragma unroll
      for (int nt = 0; nt < NT; ++nt) {
        bfrag bf = *(const bfrag*)&Wr[(size_t)((ks * NT + nt) * 64 + lane) * 8];
        acc[nt] = __builtin_amdgcn_mfma_f32_16x16x32_bf16(af[ks], bf, acc[nt], 0, 0, 0);
      }
    }
#pragma unroll
    for (int nt = 0; nt < NT; ++nt) {
      int c = nt * 16 + col0;
#pragma unroll
      for (int r = 0; r < 4; ++r) {
        int row = r0 + r;
        if (row < NN)
          Y[((size_t)rel * NN + row) * OUT + c] = f2bf(acc[nt][r]);
      }
    }
  }
}

// ---------- layer 3 phase B: flat segment-sum over all relations ----------
__global__ __launch_bounds__(256, 8) void rgcn_agg3(
    const unsigned short* __restrict__ Y,   // [(NR+1)*NN][32]
    const int* __restrict__ indptr,         // [NKEY+1]
    const int* __restrict__ gidx,           // [NE] = et*NN + src, sorted by dst
    const float* __restrict__ bias,         // [32]
    float* __restrict__ out) {              // [NN][32] f32
  int t = blockIdx.x * 256 + threadIdx.x;
  int row = t >> 2;
  if (row >= NN) return;
  int c = (t & 3) * 8;

  int beg = indptr[row * NR];
  int end = indptr[row * NR + NR];

  float s[8] = {0.f, 0.f, 0.f, 0.f, 0.f, 0.f, 0.f, 0.f};
  int e = beg;
  for (; e + 3 < end; e += 4) {
    int g0 = gidx[e], g1 = gidx[e + 1], g2 = gidx[e + 2], g3 = gidx[e + 3];
    uvec8 v0 = *(const uvec8*)&Y[(size_t)g0 * 32 + c];
    uvec8 v1 = *(const uvec8*)&Y[(size_t)g1 * 32 + c];
    uvec8 v2 = *(const uvec8*)&Y[(size_t)g2 * 32 + c];
    uvec8 v3 = *(const uvec8*)&Y[(size_t)g3 * 32 + c];
#pragma unroll
    for (int i = 0; i < 8; ++i)
      s[i] += (bf2f(v0[i]) + bf2f(v1[i])) + (bf2f(v2[i]) + bf2f(v3[i]));
  }
  for (; e < end; ++e) {
    int g = gidx[e];
    uvec8 v = *(const uvec8*)&Y[(size_t)g * 32 + c];
#pragma unroll
    for (int i = 0; i < 8; ++i) s[i] += bf2f(v[i]);
  }
  // self
  uvec8 vs = *(const uvec8*)&Y[((size_t)NR * NN + row) * 32 + c];
#pragma unroll
  for (int i = 0; i < 8; ++i) s[i] += bf2f(vs[i]);

  float4 o0, o1;
  o0.x = fmaxf(s[0] + bias[c + 0], 0.f);
  o0.y = fmaxf(s[1] + bias[c + 1], 0.f);
  o0.z = fmaxf(s[2] + bias[c + 2], 0.f);
  o0.w = fmaxf(s[3] + bias[c + 3], 0.f);
  o1.x = fmaxf(s[4] + bias[c + 4], 0.f);
  o1.y = fmaxf(s[5] + bias[c + 5], 0.f);
  o1.z = fmaxf(s[6] + bias[c + 6], 0.f);
  o1.w = fmaxf(s[7] + bias[c + 7], 0.f);
  *(float4*)&out[(size_t)row * 32 + c] = o0;
  *(float4*)&out[(size_t)row * 32 + c + 4] = o1;
}

// ---------- host ----------
static inline char* align_up(char* p, size_t a) {
  return (char*)(((size_t)p + a - 1) & ~(a - 1));
}

extern "C" void kernel_launch(void* const* d_in, const int* in_sizes, int n_in,
                              void* d_out, int out_size, void* d_ws, size_t ws_size,
                              hipStream_t stream) {
  const float* nf = (const float*)d_in[0];
  const int* src  = (const int*)d_in[1];
  const int* dst  = (const int*)d_in[2];
  const int* et   = (const int*)d_in[3];
  const float* V1 = (const float*)d_in[4];
  const float* C1 = (const float*)d_in[5];
  const float* S1 = (const float*)d_in[6];
  const float* b1 = (const float*)d_in[7];
  const float* V2 = (const float*)d_in[8];
  const float* C2 = (const float*)d_in[9];
  const float* S2 = (const float*)d_in[10];
  const float* b2 = (const float*)d_in[11];
  const float* V3 = (const float*)d_in[12];
  const float* C3 = (const float*)d_in[13];
  const float* S3 = (const float*)d_in[14];
  const float* b3 = (const float*)d_in[15];
  float* out = (float*)d_out;

  // fragment-table element counts (u16): (NR+1)*KS*NT*64*8
  constexpr int WF1 = (NR + 1) * 1 * 4 * 512;  // 14336
  constexpr int WF2 = (NR + 1) * 2 * 8 * 512;  // 57344
  constexpr int WF3 = (NR + 1) * 4 * 2 * 512;  // 28672

  char* p = (char*)d_ws;
  int* cnt = (int*)p;                p = align_up(p + (size_t)NKEY * 4, 256);  // doubles as cur
  int* indptr = (int*)p;             p = align_up(p + (size_t)(NKEY + 1) * 4, 256);
  int* partial = (int*)p;            p = align_up(p + (size_t)NCHUNK * 4, 256);
  int* sidx = (int*)p;               p = align_up(p + (size_t)NE * 4, 256);
  int* gidx = (int*)p;               p = align_up(p + (size_t)NE * 4, 256);
  unsigned short* hp = (unsigned short*)p;  p = align_up(p + (size_t)NN * 32 * 2, 256);
  unsigned short* W1 = (unsigned short*)p;  p = align_up(p + (size_t)WF1 * 2, 256);
  unsigned short* W2 = (unsigned short*)p;  p = align_up(p + (size_t)WF2 * 2, 256);
  unsigned short* W3 = (unsigned short*)p;  p = align_up(p + (size_t)WF3 * 2, 256);
  unsigned short* G1 = (unsigned short*)p;  p = align_up(p + (size_t)NN * 64 * 2, 256);
  unsigned short* G2 = (unsigned short*)p;  p = align_up(p + (size_t)NN * 128 * 2, 256);
  unsigned short* Y3 = (unsigned short*)p;  p = align_up(p + (size_t)(NR + 1) * NN * 32 * 2, 256);

  hipMemsetAsync(cnt, 0, (size_t)NKEY * 4, stream);

  const int EB = (NE + 255) / 256;  // 2344
  pad_feats_bf16<<<(NN * 4 + 255) / 256, 256, 0, stream>>>(nf, hp);
  hist2<<<EB, 256, 0, stream>>>(dst, et, cnt);
  scanA<<<NCHUNK, 256, 0, stream>>>(cnt, partial);
  scanB<<<1, 256, 0, stream>>>(partial);
  scanC<<<NCHUNK, 256, 0, stream>>>(cnt, partial, indptr, cnt);
  scatter2<<<EB, 256, 0, stream>>>(et, src, dst, cnt, sidx, gidx);

  compose_wf<26, 64, 1, 4><<<(WF1 / 8 + 255) / 256, 256, 0, stream>>>(V1, C1, S1, W1);
  compose_wf<64, 128, 2, 8><<<(WF2 / 8 + 255) / 256, 256, 0, stream>>>(V2, C2, S2, W2);
  compose_wf<128, 32, 4, 2><<<(WF3 / 8 + 255) / 256, 256, 0, stream>>>(V3, C3, S3, W3);

  const int NB16 = NN / 16;  // 6250 (exact)
  rgcn_layer_v5<32, 64, 128, 8><<<NB16, 256, 0, stream>>>(hp, W1, b1, indptr, sidx, G1);
  rgcn_layer_v5<64, 128, 128, 8><<<NB16, 256, 0, stream>>>(G1, W2, b2, indptr, sidx, G2);

  // layer 3: transform-first (IN=128 > OUT=32)
  const int NBK = (NN + 63) / 64;  // 1563
  rgcn_transform<128, 32><<<NBK, 256, 0, stream>>>(G2, W3, Y3);
  rgcn_agg3<<<(NN * 4 + 255) / 256, 256, 0, stream>>>(Y3, indptr, gidx, b3, out);

  (void)in_sizes; (void)n_in; (void)out_size; (void)ws_size;
}

// Round 10
// 184.092 us; speedup vs baseline: 1.2929x; 1.1135x over previous
//
#include <hip/hip_runtime.h>

#define NN 100000
#define NE 600000
#define NR 6
#define NB 6
#define NKEY (NN * NR)            // 600000 keys: dst*6 + etype
#define NCHUNK ((NKEY + 1023) / 1024)  // 586

typedef __attribute__((ext_vector_type(8))) short bfrag;       // 8 bf16 (4 VGPRs)
typedef __attribute__((ext_vector_type(8))) unsigned short uvec8;
typedef __attribute__((ext_vector_type(8))) unsigned char ucvec8;
typedef __attribute__((ext_vector_type(4))) float accvec;

__device__ __forceinline__ float bf2f(unsigned short u) {
  union { unsigned int i; float f; } v;
  v.i = ((unsigned int)u) << 16;
  return v.f;
}
__device__ __forceinline__ unsigned short f2bf(float f) {
  union { float f; unsigned int i; } v;
  v.f = f;
  return (unsigned short)((v.i + 0x7FFFu + ((v.i >> 16) & 1u)) >> 16);
}
__device__ __forceinline__ float fp82f(unsigned char u) {
  return __builtin_amdgcn_cvt_f32_fp8((unsigned int)u, 0);
}
__device__ __forceinline__ unsigned char f2fp8(float f) {
  return (unsigned char)(__builtin_amdgcn_cvt_pk_fp8_f32(f, 0.f, 0, false) & 0xff);
}

// ---------- W composition body (fragment layout, stacked-K) ----------
template <int IN, int OUT, int KS, int NT>
__device__ __forceinline__ void compose_body(int idx, const float* __restrict__ V,
                                             const float* __restrict__ C,
                                             const float* __restrict__ S,
                                             unsigned short* __restrict__ Wf) {
  int lane = idx & 63;
  int t = idx >> 6;
  int nt = t % NT; t /= NT;
  int ks = t % KS; int rel = t / KS;
  int n = nt * 16 + (lane & 15);
  int g = lane >> 4;
  uvec8 o;
#pragma unroll
  for (int i = 0; i < 8; ++i) {
    int k = ks * 32 + g * 8 + i;
    float s = 0.f;
    if (k < IN) {
      if (rel < NR) {
#pragma unroll
        for (int b = 0; b < NB; ++b) s += C[rel * NB + b] * V[((size_t)b * IN + k) * OUT + n];
      } else {
        s = S[(size_t)k * OUT + n];
      }
    }
    o[i] = f2bf(s);
  }
  *(uvec8*)&Wf[(size_t)idx * 8] = o;
}

// ---------- fused prep: pad_feats + hist + compose x3 ----------
#define PB_PAD 1563   // ceil(NN*4/256)
#define PB_HIST 2344  // ceil(NE/256)
__global__ __launch_bounds__(256) void prep_kernel(
    const float* __restrict__ nf, unsigned short* __restrict__ hp,
    const int* __restrict__ dst, const int* __restrict__ et, int* __restrict__ cnt,
    const float* V1, const float* C1, const float* S1, unsigned short* W1,
    const float* V2, const float* C2, const float* S2, unsigned short* W2,
    const float* V3, const float* C3, const float* S3, unsigned short* W3) {
  int b = blockIdx.x, tid = threadIdx.x;
  if (b < PB_PAD) {
    int idx = b * 256 + tid;
    if (idx < NN * 4) {
      int n = idx >> 2, c = idx & 3;
      uvec8 o;
#pragma unroll
      for (int i = 0; i < 8; ++i) {
        int k = c * 8 + i;
        o[i] = (k < 26) ? f2bf(nf[n * 26 + k]) : (unsigned short)0;
      }
      *(uvec8*)&hp[(size_t)n * 32 + c * 8] = o;
    }
  } else if (b < PB_PAD + PB_HIST) {
    int e = (b - PB_PAD) * 256 + tid;
    if (e < NE) atomicAdd(&cnt[dst[e] * NR + et[e]], 1);
  } else if (b < PB_PAD + PB_HIST + 7) {
    int idx = (b - PB_PAD - PB_HIST) * 256 + tid;  // 1792 exact
    compose_body<26, 64, 1, 4>(idx, V1, C1, S1, W1);
  } else if (b < PB_PAD + PB_HIST + 7 + 28) {
    int idx = (b - PB_PAD - PB_HIST - 7) * 256 + tid;  // 7168 exact
    compose_body<64, 128, 2, 8>(idx, V2, C2, S2, W2);
  } else {
    int idx = (b - PB_PAD - PB_HIST - 35) * 256 + tid;  // 3584 exact
    compose_body<128, 32, 4, 2>(idx, V3, C3, S3, W3);
  }
}

// ---------- CSR scan ----------
__global__ void scanA(const int* __restrict__ cnt, int* __restrict__ partial) {
  __shared__ int ts[256];
  int t = threadIdx.x;
  int base = blockIdx.x * 1024 + t * 4;
  int s = 0;
#pragma unroll
  for (int i = 0; i < 4; ++i)
    if (base + i < NKEY) s += cnt[base + i];
  ts[t] = s;
  __syncthreads();
  for (int off = 128; off; off >>= 1) {
    if (t < off) ts[t] += ts[t + off];
    __syncthreads();
  }
  if (t == 0) partial[blockIdx.x] = ts[0];
}

// scanC with inline partial prefix (replaces scanB+scanC). cur aliases cnt.
__global__ void scanC2(int* __restrict__ cnt, const int* __restrict__ partial,
                       int* __restrict__ indptr) {
  __shared__ int ts[256];
  int t = threadIdx.x;
  int bid = blockIdx.x;
  int ps = 0;
  for (int i = t; i < bid; i += 256) ps += partial[i];
  ts[t] = ps;
  __syncthreads();
  for (int off = 128; off; off >>= 1) {
    if (t < off) ts[t] += ts[t + off];
    __syncthreads();
  }
  int base = ts[0];
  __syncthreads();

  int bbase = bid * 1024 + t * 4;
  int v[4], s = 0;
#pragma unroll
  for (int i = 0; i < 4; ++i) {
    v[i] = (bbase + i < NKEY) ? cnt[bbase + i] : 0;
    s += v[i];
  }
  ts[t] = s;
  __syncthreads();
  for (int off = 1; off < 256; off <<= 1) {
    int x = (t >= off) ? ts[t - off] : 0;
    __syncthreads();
    ts[t] += x;
    __syncthreads();
  }
  int run = base + ts[t] - s;
#pragma unroll
  for (int i = 0; i < 4; ++i) {
    if (bbase + i < NKEY) {
      indptr[bbase + i] = run;
      cnt[bbase + i] = run;   // cur
      run += v[i];
    }
  }
  if (bid == 0 && t == 0) indptr[NKEY] = NE;
}

__global__ void scatter2(const int* __restrict__ et, const int* __restrict__ src,
                         const int* __restrict__ dst, int* __restrict__ cur,
                         int* __restrict__ sidx, int* __restrict__ gidx) {
  int e = blockIdx.x * 256 + threadIdx.x;
  if (e < NE) {
    int r = et[e];
    int s = src[e];
    int key = dst[e] * NR + r;
    int pos = atomicAdd(&cur[key], 1);
    sidx[pos] = s;
    gidx[pos] = r * NN + s;
  }
}

// ---------- fused layer v6: v5 structure + fp8 in/out options ----------
template <int K, int OUT, int MAXE, bool IN_FP8, bool OUT_FP8>
__global__ __launch_bounds__(256, 8) void rgcn_layer_v6(
    const void* __restrict__ hv,            // [NN][K] bf16 or fp8 (pre-relu'd)
    const unsigned short* __restrict__ Wf,  // stacked fragment table (bf16)
    const float* __restrict__ bias,         // [OUT] f32
    const int* __restrict__ indptr,         // [NKEY+1]
    const int* __restrict__ sidx,           // [NE]
    void* __restrict__ Gout) {              // [NN][OUT] bf16 or fp8
  constexpr int ROWS = 16;
  constexpr int KS = K / 32;
  constexpr int KT = 7 * KS;
  constexpr int NT = OUT / 16;
  constexpr int NTW = NT / 4;
  constexpr int KC = K / 8;
  constexpr int CT = 7 * KC;
  constexpr int ITEMS = (ROWS * CT + 255) / 256;
  constexpr int KP = 7 * K + 8;                 // A-tile row stride (bf16 elems)
  constexpr int MSB = IN_FP8 ? (K + 8) : (2 * K + 16);  // msg row stride bytes
  constexpr int ATB = ROWS * KP * 2;
  constexpr int MGB = MAXE * MSB;
  constexpr int LDSB = ATB > MGB ? ATB : MGB;
  constexpr int SITER = MAXE * KC / 256;

  __shared__ __align__(16) char buf[LDSB];      // msg buffer, then A tile
  __shared__ int seg[ROWS * NR + 1];
  unsigned short* A = (unsigned short*)buf;

  const int tid = threadIdx.x;
  const int row0 = blockIdx.x * ROWS;

  if (tid < ROWS * NR + 1) seg[tid] = indptr[row0 * NR + tid];
  __syncthreads();

  const int E0 = seg[0];
  const int E1 = seg[ROWS * NR];

  float sum[ITEMS][8];
#pragma unroll
  for (int i = 0; i < ITEMS; ++i)
#pragma unroll
    for (int q = 0; q < 8; ++q) sum[i][q] = 0.f;

  for (int b0 = E0; b0 < E1; b0 += MAXE) {
    const int bcount = min(MAXE, E1 - b0);
    __syncthreads();  // msg free

    // stage: static unrolled flat gather (independent loads; clamp tail)
#pragma unroll
    for (int i = 0; i < SITER; ++i) {
      int idx = tid + i * 256;
      int e = idx / KC;
      int c = idx & (KC - 1);
      int ec = min(e, bcount - 1);
      int s = sidx[b0 + ec];
      if constexpr (IN_FP8) {
        *(ucvec8*)&buf[e * MSB + c * 8] =
            *(const ucvec8*)((const unsigned char*)hv + (size_t)s * K + c * 8);
      } else {
        *(uvec8*)&buf[e * MSB + c * 16] =
            *(const uvec8*)((const unsigned short*)hv + (size_t)s * K + c * 8);
      }
    }
    __syncthreads();

    // accumulate from LDS into per-thread fp32 regs
#pragma unroll
    for (int i = 0; i < ITEMS; ++i) {
      int idx = tid + i * 256;
      if (idx < ROWS * CT) {
        int row = idx / CT, chunk = idx % CT;
        if (chunk < 6 * KC) {
          int rel = chunk / KC, c = chunk & (KC - 1);
          int beg = seg[row * NR + rel], end = seg[row * NR + rel + 1];
          int lo = max(beg, b0), hi = min(end, b0 + bcount);
          for (int e = lo; e < hi; ++e) {
            if constexpr (IN_FP8) {
              ucvec8 t = *(const ucvec8*)&buf[(e - b0) * MSB + c * 8];
#pragma unroll
              for (int q = 0; q < 8; ++q) sum[i][q] += fp82f(t[q]);
            } else {
              uvec8 t = *(const uvec8*)&buf[(e - b0) * MSB + c * 16];
#pragma unroll
              for (int q = 0; q < 8; ++q) sum[i][q] += bf2f(t[q]);
            }
          }
        }
      }
    }
  }

  __syncthreads();  // msg buffer reusable as A tile

  // pack stacked bf16 A tile
#pragma unroll
  for (int i = 0; i < ITEMS; ++i) {
    int idx = tid + i * 256;
    if (idx < ROWS * CT) {
      int row = idx / CT, chunk = idx % CT;
      uvec8 o;
      if (chunk >= 6 * KC) {  // self section
        int c = chunk - 6 * KC;
        if constexpr (IN_FP8) {
          ucvec8 tv = *(const ucvec8*)((const unsigned char*)hv +
                                       (size_t)(row0 + row) * K + c * 8);
#pragma unroll
          for (int q = 0; q < 8; ++q) o[q] = f2bf(fp82f(tv[q]));
        } else {
          o = *(const uvec8*)((const unsigned short*)hv + (size_t)(row0 + row) * K + c * 8);
        }
      } else {
#pragma unroll
        for (int q = 0; q < 8; ++q) o[q] = f2bf(sum[i][q]);
      }
      *(uvec8*)&A[row * KP + chunk * 8] = o;
    }
  }
  __syncthreads();

  // dense MFMA sweep over stacked K; waves split OUT 4-ways
  const int lane = tid & 63;
  const int wv = tid >> 6;
  const int abase = (lane & 15) * KP + (lane >> 4) * 8;

  accvec acc[NTW];
#pragma unroll
  for (int j = 0; j < NTW; ++j) acc[j] = 0.f;

#pragma unroll
  for (int kst = 0; kst < KT; ++kst) {
    bfrag af = *(const bfrag*)&A[abase + kst * 32];
#pragma unroll
    for (int j = 0; j < NTW; ++j) {
      int nt = wv * NTW + j;
      bfrag bf = *(const bfrag*)&Wf[(size_t)((kst * NT + nt) * 64 + lane) * 8];
      acc[j] = __builtin_amdgcn_mfma_f32_16x16x32_bf16(af, bf, acc[j], 0, 0, 0);
    }
  }

  // epilogue: bias + relu; D layout col=lane&15, row=(lane>>4)*4+reg
  const int r0 = row0 + (lane >> 4) * 4;
  const int col0 = lane & 15;
#pragma unroll
  for (int j = 0; j < NTW; ++j) {
    int c = (wv * NTW + j) * 16 + col0;
    float bv = bias[c];
#pragma unroll
    for (int r = 0; r < 4; ++r) {
      float v = fmaxf(acc[j][r] + bv, 0.f);
      if constexpr (OUT_FP8)
        ((unsigned char*)Gout)[(size_t)(r0 + r) * OUT + c] = f2fp8(v);
      else
        ((unsigned short*)Gout)[(size_t)(r0 + r) * OUT + c] = f2bf(v);
    }
  }
}

// ---------- layer 3 phase A: dense per-relation transform ----------
template <int K, int OUT>
__global__ __launch_bounds__(256, 4) void rgcn_transform(
    const unsigned short* __restrict__ h,   // [NN][K] bf16 (pre-relu'd)
    const unsigned short* __restrict__ Wf,  // fragment layout, NR+1 rels
    unsigned short* __restrict__ Y) {       // [(NR+1)*NN][OUT]
  constexpr int KS = K / 32;
  constexpr int NT = OUT / 16;
  constexpr int KC = K / 8;
  constexpr int KP = K + 8;

  __shared__ unsigned short Asm[64 * KP];
  const int tid = threadIdx.x;
  const int row0 = blockIdx.x * 64;

  for (int idx = tid; idx < 64 * KC; idx += 256) {
    int j = idx / KC, c = idx - (idx / KC) * KC;
    int row = row0 + j;
    uvec8 o = 0;
    if (row < NN) o = *(const uvec8*)&h[(size_t)row * K + c * 8];
    *(uvec8*)&Asm[j * KP + c * 8] = o;
  }
  __syncthreads();

  const int lane = tid & 63;
  const int wv = tid >> 6;
  const int abase = (wv * 16 + (lane & 15)) * KP + (lane >> 4) * 8;

  bfrag af[KS];
#pragma unroll
  for (int ks = 0; ks < KS; ++ks) af[ks] = *(const bfrag*)&Asm[abase + ks * 32];

  const int r0 = row0 + wv * 16 + (lane >> 4) * 4;
  const int col0 = lane & 15;

  for (int rel = 0; rel <= NR; ++rel) {
    accvec acc[NT];
#pragma unroll
    for (int nt = 0; nt < NT; ++nt) acc[nt] = 0.f;
    const unsigned short* Wr = Wf + (size_t)rel * KS * NT * 512;
#pragma unroll
    for (int ks = 0; ks < KS; ++ks) {
#pragma unroll
      for (int nt = 0; nt < NT; ++nt) {
        bfrag bf = *(const bfrag*)&Wr[(size_t)((ks * NT + nt) * 64 + lane) * 8];
        acc[nt] = __builtin_amdgcn_mfma_f32_16x16x32_bf16(af[ks], bf, acc[nt], 0, 0, 0);
      }
    }
#pragma unroll
    for (int nt = 0; nt < NT; ++nt) {
      int c = nt * 16 + col0;
#pragma unroll
      for (int r = 0; r < 4; ++r) {
        int row = r0 + r;
        if (row < NN)
          Y[((size_t)rel * NN + row) * OUT + c] = f2bf(acc[nt][r]);
      }
    }
  }
}

// ---------- layer 3 phase B: flat segment-sum over all relations ----------
__global__ __launch_bounds__(256, 8) void rgcn_agg3(
    const unsigned short* __restrict__ Y,   // [(NR+1)*NN][32]
    const int* __restrict__ indptr,         // [NKEY+1]
    const int* __restrict__ gidx,           // [NE] = et*NN + src, sorted by dst
    const float* __restrict__ bias,         // [32]
    float* __restrict__ out) {              // [NN][32] f32
  int t = blockIdx.x * 256 + threadIdx.x;
  int row = t >> 2;
  if (row >= NN) return;
  int c = (t & 3) * 8;

  int beg = indptr[row * NR];
  int end = indptr[row * NR + NR];

  float s[8] = {0.f, 0.f, 0.f, 0.f, 0.f, 0.f, 0.f, 0.f};
  int e = beg;
  for (; e + 3 < end; e += 4) {
    int g0 = gidx[e], g1 = gidx[e + 1], g2 = gidx[e + 2], g3 = gidx[e + 3];
    uvec8 v0 = *(const uvec8*)&Y[(size_t)g0 * 32 + c];
    uvec8 v1 = *(const uvec8*)&Y[(size_t)g1 * 32 + c];
    uvec8 v2 = *(const uvec8*)&Y[(size_t)g2 * 32 + c];
    uvec8 v3 = *(const uvec8*)&Y[(size_t)g3 * 32 + c];
#pragma unroll
    for (int i = 0; i < 8; ++i)
      s[i] += (bf2f(v0[i]) + bf2f(v1[i])) + (bf2f(v2[i]) + bf2f(v3[i]));
  }
  for (; e < end; ++e) {
    int g = gidx[e];
    uvec8 v = *(const uvec8*)&Y[(size_t)g * 32 + c];
#pragma unroll
    for (int i = 0; i < 8; ++i) s[i] += bf2f(v[i]);
  }
  // self
  uvec8 vs = *(const uvec8*)&Y[((size_t)NR * NN + row) * 32 + c];
#pragma unroll
  for (int i = 0; i < 8; ++i) s[i] += bf2f(vs[i]);

  float4 o0, o1;
  o0.x = fmaxf(s[0] + bias[c + 0], 0.f);
  o0.y = fmaxf(s[1] + bias[c + 1], 0.f);
  o0.z = fmaxf(s[2] + bias[c + 2], 0.f);
  o0.w = fmaxf(s[3] + bias[c + 3], 0.f);
  o1.x = fmaxf(s[4] + bias[c + 4], 0.f);
  o1.y = fmaxf(s[5] + bias[c + 5], 0.f);
  o1.z = fmaxf(s[6] + bias[c + 6], 0.f);
  o1.w = fmaxf(s[7] + bias[c + 7], 0.f);
  *(float4*)&out[(size_t)row * 32 + c] = o0;
  *(float4*)&out[(size_t)row * 32 + c + 4] = o1;
}

// ---------- host ----------
static inline char* align_up(char* p, size_t a) {
  return (char*)(((size_t)p + a - 1) & ~(a - 1));
}

extern "C" void kernel_launch(void* const* d_in, const int* in_sizes, int n_in,
                              void* d_out, int out_size, void* d_ws, size_t ws_size,
                              hipStream_t stream) {
  const float* nf = (const float*)d_in[0];
  const int* src  = (const int*)d_in[1];
  const int* dst  = (const int*)d_in[2];
  const int* et   = (const int*)d_in[3];
  const float* V1 = (const float*)d_in[4];
  const float* C1 = (const float*)d_in[5];
  const float* S1 = (const float*)d_in[6];
  const float* b1 = (const float*)d_in[7];
  const float* V2 = (const float*)d_in[8];
  const float* C2 = (const float*)d_in[9];
  const float* S2 = (const float*)d_in[10];
  const float* b2 = (const float*)d_in[11];
  const float* V3 = (const float*)d_in[12];
  const float* C3 = (const float*)d_in[13];
  const float* S3 = (const float*)d_in[14];
  const float* b3 = (const float*)d_in[15];
  float* out = (float*)d_out;

  // fragment-table element counts (u16): (NR+1)*KS*NT*64*8
  constexpr int WF1 = (NR + 1) * 1 * 4 * 512;  // 14336
  constexpr int WF2 = (NR + 1) * 2 * 8 * 512;  // 57344
  constexpr int WF3 = (NR + 1) * 4 * 2 * 512;  // 28672

  char* p = (char*)d_ws;
  int* cnt = (int*)p;                p = align_up(p + (size_t)NKEY * 4, 256);  // doubles as cur
  int* indptr = (int*)p;             p = align_up(p + (size_t)(NKEY + 1) * 4, 256);
  int* partial = (int*)p;            p = align_up(p + (size_t)NCHUNK * 4, 256);
  int* sidx = (int*)p;               p = align_up(p + (size_t)NE * 4, 256);
  int* gidx = (int*)p;               p = align_up(p + (size_t)NE * 4, 256);
  unsigned short* hp = (unsigned short*)p;  p = align_up(p + (size_t)NN * 32 * 2, 256);
  unsigned short* W1 = (unsigned short*)p;  p = align_up(p + (size_t)WF1 * 2, 256);
  unsigned short* W2 = (unsigned short*)p;  p = align_up(p + (size_t)WF2 * 2, 256);
  unsigned short* W3 = (unsigned short*)p;  p = align_up(p + (size_t)WF3 * 2, 256);
  unsigned char* G1 = (unsigned char*)p;    p = align_up(p + (size_t)NN * 64, 256);   // fp8
  unsigned short* G2 = (unsigned short*)p;  p = align_up(p + (size_t)NN * 128 * 2, 256);
  unsigned short* Y3 = (unsigned short*)p;  p = align_up(p + (size_t)(NR + 1) * NN * 32 * 2, 256);

  hipMemsetAsync(cnt, 0, (size_t)NKEY * 4, stream);

  const int EB = (NE + 255) / 256;  // 2344
  // fused prep: pad(1563) + hist(2344) + compose(7+28+14)
  prep_kernel<<<PB_PAD + PB_HIST + 49, 256, 0, stream>>>(
      nf, hp, dst, et, cnt, V1, C1, S1, W1, V2, C2, S2, W2, V3, C3, S3, W3);
  scanA<<<NCHUNK, 256, 0, stream>>>(cnt, partial);
  scanC2<<<NCHUNK, 256, 0, stream>>>(cnt, partial, indptr);
  scatter2<<<EB, 256, 0, stream>>>(et, src, dst, cnt, sidx, gidx);

  const int NB16 = NN / 16;  // 6250 (exact)
  rgcn_layer_v6<32, 64, 128, false, true><<<NB16, 256, 0, stream>>>(
      hp, W1, b1, indptr, sidx, G1);
  rgcn_layer_v6<64, 128, 128, true, false><<<NB16, 256, 0, stream>>>(
      G1, W2, b2, indptr, sidx, G2);

  // layer 3: transform-first (IN=128 > OUT=32)
  const int NBK = (NN + 63) / 64;  // 1563
  rgcn_transform<128, 32><<<NBK, 256, 0, stream>>>(G2, W3, Y3);
  rgcn_agg3<<<(NN * 4 + 255) / 256, 256, 0, stream>>>(Y3, indptr, gidx, b3, out);

  (void)in_sizes; (void)n_in; (void)out_size; (void)ws_size;
}